// Round 3
// baseline (292.327 us; speedup 1.0000x reference)
//
#include <hip/hip_runtime.h>

// Siamese GeoCheby, round 3:
//  - conv split: k_csr (CSR->global) -> k_g1 (gather1, 4 blk/graph) -> k_g2 (H1/P + gather2)
//  - gather sources in fp32 LDS, float4 reads (all 32 banks, ~free) vs round-2 8-way conflicts
//  - fc2 on bf16 MFMA (split-K 8); k_xw regrouped to 4-wave blocks
//  - per-node P = h@w4_0 + b4 precomputed so gather2 epilogue is one float4 read

#define NN   268
#define EE   8576
#define NG   192
#define FDIM 4288        // 268*16

typedef __bf16 bf16_t;
typedef bf16_t bf16x8 __attribute__((ext_vector_type(8)));
typedef bf16_t bf16x4 __attribute__((ext_vector_type(4)));
typedef float  f32x4  __attribute__((ext_vector_type(4)));

// ---- workspace layout (float32 slots) ----
#define XW0_OFF  0                       // 192*4288 f32 (xw0); later reused by FB
#define XW1B_OFF 823296                  // 192*4288 bf16 = 411648 f
#define WB_OFF   1234944                 // 1024*4288 bf16 = 2195456 f; later reused by R2P
#define WB2_OFF  3430400                 // 512*1024 bf16 = 262144 f
#define WXT_OFF  3692544                 // 2*9*64*8 bf16 = 4608 f
#define EPK_OFF  3697152                 // 192*8576 u32 = 1646592 f; later reused by R1P
#define OFFS_OFF 5343744                 // 192*269 int = 51648 f
#define HB_OFF   5395392                 // 192*4288 bf16 = 411648 f
#define H1B_OFF  5807040                 // 192*1024 bf16 = 98304 f
#define WS_TOP   5905344                 // ~23.6 MB
#define R1P_OFF  EPK_OFF                 // 4*192*1024 f32 = 786432 (epk/offs dead)
#define R2P_OFF  WB_OFF                  // 8*192*512 f32 = 786432 (wb dead)
#define FB_OFF   XW0_OFF                 // 192*4288 bf16 (xw0 dead)

#define NCASTB  2144    // fc1w cast blocks (2144*2048 = 1024*4288)
#define NCASTB2 256     // fc2w cast blocks (256*2048 = 512*1024)

// ---------------------------------------------------------------------------
// K0: cast fc1_w + fc2_w to bf16; build MFMA B-fragments of [w0|w1]
// ---------------------------------------------------------------------------
__global__ __launch_bounds__(256) void k_prep(
    const float* __restrict__ fc1w, const float* __restrict__ fc2w,
    const float* __restrict__ gc1w,
    bf16_t* __restrict__ wb, bf16_t* __restrict__ wb2, bf16_t* __restrict__ wxt)
{
    if (blockIdx.x < NCASTB + NCASTB2) {
        const float* src; bf16_t* dst; size_t base;
        if (blockIdx.x < NCASTB) {
            src = fc1w; dst = wb;
            base = ((size_t)blockIdx.x * 256 + threadIdx.x) * 8;
        } else {
            src = fc2w; dst = wb2;
            base = ((size_t)(blockIdx.x - NCASTB) * 256 + threadIdx.x) * 8;
        }
        const float4 a = *(const float4*)(src + base);
        const float4 b = *(const float4*)(src + base + 4);
        bf16x8 v;
        v[0] = (bf16_t)a.x; v[1] = (bf16_t)a.y; v[2] = (bf16_t)a.z; v[3] = (bf16_t)a.w;
        v[4] = (bf16_t)b.x; v[5] = (bf16_t)b.y; v[6] = (bf16_t)b.z; v[7] = (bf16_t)b.w;
        *(bf16x8*)(dst + base) = v;
    } else {
        // B-frag for 16x16x32: lane holds B[k=(lane>>4)*8+j][n=lane&15]
        for (int idx = threadIdx.x; idx < 2 * 9 * 64; idx += 256) {
            const int lane = idx & 63, chunk = (idx >> 6) % 9, nt = idx / (9 * 64);
            const int n = lane & 15, q = lane >> 4;
            bf16x8 v;
#pragma unroll
            for (int j = 0; j < 8; ++j) {
                const int k = chunk * 32 + q * 8 + j;
                v[j] = (k < NN) ? (bf16_t)gc1w[nt * FDIM + k * 16 + n] : (bf16_t)0.f;
            }
            *(bf16x8*)(wxt + (size_t)idx * 8) = v;
        }
    }
}

// ---------------------------------------------------------------------------
// K1: CSR build per graph -> global packed edges (col<<16 | bf16(norm)) + offs
// ---------------------------------------------------------------------------
__global__ __launch_bounds__(256) void k_csr(
    const int* __restrict__ ei0, const int* __restrict__ ei1, const int* __restrict__ ei2,
    const float* __restrict__ ea0, const float* __restrict__ ea1, const float* __restrict__ ea2,
    unsigned* __restrict__ epk, int* __restrict__ offsg)
{
    const int g = blockIdx.x;
    const int br = g >> 6, b = g & 63;
    const int*   ei = (br == 0) ? ei0 : (br == 1) ? ei1 : ei2;
    const float* ea = (br == 0) ? ea0 : (br == 1) ? ea1 : ea2;
    const int*   rowp = ei + (size_t)b * (2 * EE);
    const int*   colp = rowp + EE;
    const float* eap  = ea + (size_t)b * EE;

    __shared__ float degS[NN];
    __shared__ int   cntS[NN];
    __shared__ int   offS[NN + 1];
    __shared__ int   curS[NN];
    const int tid = threadIdx.x;

    for (int n = tid; n < NN; n += 256) { degS[n] = 0.f; cntS[n] = 0; }
    __syncthreads();
    for (int e = tid; e < EE; e += 256) {
        const int r = rowp[e];
        atomicAdd(&degS[r], eap[e]);
        atomicAdd(&cntS[r], 1);
    }
    // inclusive scan of cntS
    for (int st = 1; st < NN; st <<= 1) {
        __syncthreads();
        int v0 = 0, v1 = 0;
        const int n0i = tid, n1i = tid + 256;
        if (n0i < NN) { v0 = cntS[n0i]; if (n0i >= st) v0 += cntS[n0i - st]; }
        if (n1i < NN) { v1 = cntS[n1i]; if (n1i >= st) v1 += cntS[n1i - st]; }
        __syncthreads();
        if (n0i < NN) cntS[n0i] = v0;
        if (n1i < NN) cntS[n1i] = v1;
    }
    __syncthreads();
    for (int n = tid; n < NN; n += 256) offS[n + 1] = cntS[n];
    if (tid == 0) offS[0] = 0;
    __syncthreads();
    for (int n = tid; n < NN; n += 256) {
        curS[n] = offS[n];
        const float d = degS[n];
        degS[n] = (d > 0.f) ? rsqrtf(d) : 0.f;
    }
    __syncthreads();
    unsigned* eg = epk + (size_t)g * EE;
    for (int e = tid; e < EE; e += 256) {
        const int r = rowp[e], c = colp[e];
        const float nv = -eap[e] * degS[r] * degS[c];
        union { float f; unsigned u; } cv; cv.f = nv;
        const unsigned bits = (cv.u + 0x7fffu + ((cv.u >> 16) & 1u)) >> 16;   // RNE
        const int pos = atomicAdd(&curS[r], 1);
        eg[pos] = ((unsigned)c << 16) | bits;
    }
    int* og = offsg + g * (NN + 1);
    for (int n = tid; n <= NN; n += 256) og[n] = offS[n];
}

// ---------------------------------------------------------------------------
// K2: xw = x @ [w0|w1] via MFMA. 4 waves/block, wave = one 16-row m-tile.
// xw0 -> f32 row-major; xw1 -> bf16 row-major.
// ---------------------------------------------------------------------------
__global__ __launch_bounds__(256) void k_xw(
    const float* __restrict__ x0, const float* __restrict__ x1, const float* __restrict__ x2,
    const bf16_t* __restrict__ wxt, float* __restrict__ xw0, bf16_t* __restrict__ xw1b)
{
    const int g = blockIdx.y;
    const int br = g >> 6, b = g & 63;
    const float* x = ((br == 0) ? x0 : (br == 1) ? x1 : x2) + (size_t)b * (NN * NN);
    const int wave = threadIdx.x >> 6, lane = threadIdx.x & 63;
    const int tile = blockIdx.x * 4 + wave;
    if (tile >= 17) return;
    const int q = lane >> 4, nlo = lane & 15;
    const int mrow = tile * 16 + nlo;
    const bool mvalid = (mrow < NN);
    const float* xrow = x + (size_t)mrow * NN;

    f32x4 acc0 = {0.f, 0.f, 0.f, 0.f}, acc1 = {0.f, 0.f, 0.f, 0.f};
    for (int ch = 0; ch < 9; ++ch) {
        const int k0 = ch * 32 + q * 8;
        float4 p0 = make_float4(0.f, 0.f, 0.f, 0.f);
        float4 p1 = make_float4(0.f, 0.f, 0.f, 0.f);
        if (mvalid) {
            if (k0 < NN)     p0 = *(const float4*)(xrow + k0);
            if (k0 + 4 < NN) p1 = *(const float4*)(xrow + k0 + 4);
        }
        bf16x8 a;
        a[0] = (bf16_t)p0.x; a[1] = (bf16_t)p0.y; a[2] = (bf16_t)p0.z; a[3] = (bf16_t)p0.w;
        a[4] = (bf16_t)p1.x; a[5] = (bf16_t)p1.y; a[6] = (bf16_t)p1.z; a[7] = (bf16_t)p1.w;
        const bf16x8 b0 = *(const bf16x8*)(wxt + (size_t)(ch * 64 + lane) * 8);
        const bf16x8 b1 = *(const bf16x8*)(wxt + (size_t)(576 + ch * 64 + lane) * 8);
        acc0 = __builtin_amdgcn_mfma_f32_16x16x32_bf16(a, b0, acc0, 0, 0, 0);
        acc1 = __builtin_amdgcn_mfma_f32_16x16x32_bf16(a, b1, acc1, 0, 0, 0);
    }
    const int col = nlo;
#pragma unroll
    for (int r = 0; r < 4; ++r) {
        const int row = tile * 16 + q * 4 + r;
        if (row < NN) {
            xw0[((size_t)g * NN + row) * 16 + col]  = acc0[r];
            xw1b[((size_t)g * NN + row) * 16 + col] = (bf16_t)acc1[r];
        }
    }
}

// ---------------------------------------------------------------------------
// K3: gather1 (4 blocks/graph, 67 nodes each): h = relu(xw0 + L@xw1 + b1) -> hb bf16
// A_s fp32 in LDS, float4 reads (conflict-free); edges from global (L2-hot)
// ---------------------------------------------------------------------------
__global__ __launch_bounds__(256) void k_g1(
    const bf16_t* __restrict__ xw1b, const float* __restrict__ xw0,
    const unsigned* __restrict__ epk, const int* __restrict__ offsg,
    const float* __restrict__ gc1b, bf16_t* __restrict__ hb)
{
    const int g = blockIdx.y, c0 = blockIdx.x * 67;
    __shared__ __align__(16) float A_s[FDIM];
    __shared__ int off_s[68];
    __shared__ float b1_s[16];
    const int tid = threadIdx.x;

    const bf16x8* src = (const bf16x8*)(xw1b + (size_t)g * FDIM);
    for (int i = tid; i < FDIM / 8; i += 256) {
        const bf16x8 v = src[i];
        float4 lo, hi;
        lo.x = (float)v[0]; lo.y = (float)v[1]; lo.z = (float)v[2]; lo.w = (float)v[3];
        hi.x = (float)v[4]; hi.y = (float)v[5]; hi.z = (float)v[6]; hi.w = (float)v[7];
        *(float4*)&A_s[i * 8]     = lo;
        *(float4*)&A_s[i * 8 + 4] = hi;
    }
    if (tid < 68) off_s[tid] = offsg[g * (NN + 1) + c0 + tid];
    if (tid < 16) b1_s[tid] = gc1b[tid];
    __syncthreads();

    const int j4 = tid & 3, nl = tid >> 2;
    const unsigned* ep = epk + (size_t)g * EE;
    const float4* A4 = (const float4*)A_s;
    const float4* xw0g = (const float4*)(xw0 + (size_t)g * FDIM);

    for (int nn = nl; nn < 67; nn += 64) {
        const int n = c0 + nn;
        const int s = off_s[nn], e = off_s[nn + 1];
        float ax = 0.f, ay = 0.f, az = 0.f, aw = 0.f;
        int i = s;
        for (; i + 1 < e; i += 2) {
            const unsigned p0 = ep[i], p1 = ep[i + 1];
            const float w0 = __uint_as_float(p0 << 16);
            const float w1 = __uint_as_float(p1 << 16);
            const float4 a0 = A4[(p0 >> 16) * 4 + j4];
            const float4 a1 = A4[(p1 >> 16) * 4 + j4];
            ax += w0 * a0.x + w1 * a1.x;
            ay += w0 * a0.y + w1 * a1.y;
            az += w0 * a0.z + w1 * a1.z;
            aw += w0 * a0.w + w1 * a1.w;
        }
        if (i < e) {
            const unsigned p0 = ep[i];
            const float w0 = __uint_as_float(p0 << 16);
            const float4 a0 = A4[(p0 >> 16) * 4 + j4];
            ax += w0 * a0.x; ay += w0 * a0.y; az += w0 * a0.z; aw += w0 * a0.w;
        }
        const float4 xv = xw0g[n * 4 + j4];
        bf16x4 h;
        h[0] = (bf16_t)fmaxf(xv.x + ax + b1_s[j4 * 4 + 0], 0.f);
        h[1] = (bf16_t)fmaxf(xv.y + ay + b1_s[j4 * 4 + 1], 0.f);
        h[2] = (bf16_t)fmaxf(xv.z + az + b1_s[j4 * 4 + 2], 0.f);
        h[3] = (bf16_t)fmaxf(xv.w + aw + b1_s[j4 * 4 + 3], 0.f);
        *(bf16x4*)(hb + (size_t)g * FDIM + n * 16 + j4 * 4) = h;
    }
}

// ---------------------------------------------------------------------------
// K4: gather2 (4 blocks/graph): H1 = h@w4_1, P = h@w4_0+b4 (per-node, vectorized),
// then f = P + L@H1 -> fb bf16
// ---------------------------------------------------------------------------
__global__ __launch_bounds__(256) void k_g2(
    const bf16_t* __restrict__ hb, const unsigned* __restrict__ epk,
    const int* __restrict__ offsg, const float* __restrict__ gc4w,
    const float* __restrict__ gc4b, bf16_t* __restrict__ fb)
{
    const int g = blockIdx.y, c0 = blockIdx.x * 67;
    __shared__ __align__(16) float H1_s[FDIM];
    __shared__ __align__(16) float P_s[FDIM];
    __shared__ float w4_s[512];
    __shared__ int off_s[68];
    __shared__ float b4_s[16];
    const int tid = threadIdx.x;

    for (int i = tid; i < 512; i += 256) w4_s[i] = gc4w[i];
    if (tid < 68) off_s[tid] = offsg[g * (NN + 1) + c0 + tid];
    if (tid < 16) b4_s[tid] = gc4b[tid];
    __syncthreads();

    // per-node H1 and P (h row read coalesced from global; w4 reads broadcast)
    for (int n = tid; n < NN; n += 256) {
        const bf16x8 h0 = *(const bf16x8*)(hb + (size_t)g * FDIM + n * 16);
        const bf16x8 h1 = *(const bf16x8*)(hb + (size_t)g * FDIM + n * 16 + 8);
        float hr[16];
#pragma unroll
        for (int j = 0; j < 8; ++j) { hr[j] = (float)h0[j]; hr[8 + j] = (float)h1[j]; }
#pragma unroll
        for (int jb = 0; jb < 4; ++jb) {
            float4 p = *(const float4*)&b4_s[jb * 4];
            float4 a = make_float4(0.f, 0.f, 0.f, 0.f);
#pragma unroll
            for (int k = 0; k < 16; ++k) {
                const float4 w0v = *(const float4*)&w4_s[k * 16 + jb * 4];
                const float4 w1v = *(const float4*)&w4_s[256 + k * 16 + jb * 4];
                const float hv = hr[k];
                p.x += hv * w0v.x; p.y += hv * w0v.y; p.z += hv * w0v.z; p.w += hv * w0v.w;
                a.x += hv * w1v.x; a.y += hv * w1v.y; a.z += hv * w1v.z; a.w += hv * w1v.w;
            }
            *(float4*)&P_s[n * 16 + jb * 4]  = p;
            *(float4*)&H1_s[n * 16 + jb * 4] = a;
        }
    }
    __syncthreads();

    const int j4 = tid & 3, nl = tid >> 2;
    const unsigned* ep = epk + (size_t)g * EE;
    const float4* A4 = (const float4*)H1_s;

    for (int nn = nl; nn < 67; nn += 64) {
        const int n = c0 + nn;
        const int s = off_s[nn], e = off_s[nn + 1];
        float ax = 0.f, ay = 0.f, az = 0.f, aw = 0.f;
        int i = s;
        for (; i + 1 < e; i += 2) {
            const unsigned p0 = ep[i], p1 = ep[i + 1];
            const float w0 = __uint_as_float(p0 << 16);
            const float w1 = __uint_as_float(p1 << 16);
            const float4 a0 = A4[(p0 >> 16) * 4 + j4];
            const float4 a1 = A4[(p1 >> 16) * 4 + j4];
            ax += w0 * a0.x + w1 * a1.x;
            ay += w0 * a0.y + w1 * a1.y;
            az += w0 * a0.z + w1 * a1.z;
            aw += w0 * a0.w + w1 * a1.w;
        }
        if (i < e) {
            const unsigned p0 = ep[i];
            const float w0 = __uint_as_float(p0 << 16);
            const float4 a0 = A4[(p0 >> 16) * 4 + j4];
            ax += w0 * a0.x; ay += w0 * a0.y; az += w0 * a0.z; aw += w0 * a0.w;
        }
        const float4 pv = *(const float4*)&P_s[n * 16 + j4 * 4];
        bf16x4 o;
        o[0] = (bf16_t)(pv.x + ax); o[1] = (bf16_t)(pv.y + ay);
        o[2] = (bf16_t)(pv.z + az); o[3] = (bf16_t)(pv.w + aw);
        *(bf16x4*)(fb + (size_t)g * FDIM + n * 16 + j4 * 4) = o;
    }
}

// ---------------------------------------------------------------------------
// K5: fc1 MFMA: r1p[kz][192][1024] = fb @ wb^T (K-slice), plain stores
// ---------------------------------------------------------------------------
__global__ __launch_bounds__(256) void k_fc1(
    const bf16_t* __restrict__ fb, const bf16_t* __restrict__ wb, float* __restrict__ r1p)
{
    const int mt = blockIdx.x, nb = blockIdx.y, kz = blockIdx.z;
    const int wid = threadIdx.x >> 6, lane = threadIdx.x & 63;
    const int q = lane >> 4, nlo = lane & 15;
    const int n0 = nb * 256 + wid * 64;
    const int cstart = (kz < 2) ? kz * 34 : 68 + (kz - 2) * 33;
    const int ccnt   = (kz < 2) ? 34 : 33;

    const bf16_t* arow = fb + (size_t)(mt * 16 + nlo) * FDIM + q * 8;
    const bf16_t* brow = wb + (size_t)(n0 + nlo) * FDIM + q * 8;
    f32x4 acc[4];
#pragma unroll
    for (int t = 0; t < 4; ++t) { acc[t][0]=0.f; acc[t][1]=0.f; acc[t][2]=0.f; acc[t][3]=0.f; }

    for (int ch = 0; ch < ccnt; ++ch) {
        const size_t ko = (size_t)(cstart + ch) * 32;
        const bf16x8 a = *(const bf16x8*)(arow + ko);
#pragma unroll
        for (int t = 0; t < 4; ++t) {
            const bf16x8 bv = *(const bf16x8*)(brow + (size_t)t * 16 * FDIM + ko);
            acc[t] = __builtin_amdgcn_mfma_f32_16x16x32_bf16(a, bv, acc[t], 0, 0, 0);
        }
    }
    float* outp = r1p + (size_t)kz * (NG * 1024);
#pragma unroll
    for (int t = 0; t < 4; ++t)
#pragma unroll
        for (int r = 0; r < 4; ++r)
            outp[(size_t)(mt * 16 + q * 4 + r) * 1024 + n0 + t * 16 + nlo] = acc[t][r];
}

// K6: h1b = bf16(relu(sum_kz r1p + fc1_b))
__global__ __launch_bounds__(256) void k_red1(
    const float* __restrict__ r1p, const float* __restrict__ b1, bf16_t* __restrict__ h1b)
{
    const size_t i = ((size_t)blockIdx.x * 256 + threadIdx.x) * 4;
    const size_t S = (size_t)NG * 1024;
    const float4 s0 = *(const float4*)(r1p + i);
    const float4 s1 = *(const float4*)(r1p + S + i);
    const float4 s2 = *(const float4*)(r1p + 2 * S + i);
    const float4 s3 = *(const float4*)(r1p + 3 * S + i);
    const float4 bb = *(const float4*)(b1 + (i & 1023));
    bf16x4 o;
    o[0] = (bf16_t)fmaxf(s0.x + s1.x + s2.x + s3.x + bb.x, 0.f);
    o[1] = (bf16_t)fmaxf(s0.y + s1.y + s2.y + s3.y + bb.y, 0.f);
    o[2] = (bf16_t)fmaxf(s0.z + s1.z + s2.z + s3.z + bb.z, 0.f);
    o[3] = (bf16_t)fmaxf(s0.w + s1.w + s2.w + s3.w + bb.w, 0.f);
    *(bf16x4*)(h1b + i) = o;
}

// K7: fc2 MFMA: r2p[kz][192][512] = h1b @ wb2^T (K-slice), plain stores
__global__ __launch_bounds__(256) void k_fc2m(
    const bf16_t* __restrict__ h1b, const bf16_t* __restrict__ wb2, float* __restrict__ r2p)
{
    const int mt = blockIdx.x, nb = blockIdx.y, kz = blockIdx.z;
    const int wid = threadIdx.x >> 6, lane = threadIdx.x & 63;
    const int q = lane >> 4, nlo = lane & 15;
    const int n0 = nb * 256 + wid * 64;

    const bf16_t* arow = h1b + (size_t)(mt * 16 + nlo) * 1024 + q * 8;
    const bf16_t* brow = wb2 + (size_t)(n0 + nlo) * 1024 + q * 8;
    f32x4 acc[4];
#pragma unroll
    for (int t = 0; t < 4; ++t) { acc[t][0]=0.f; acc[t][1]=0.f; acc[t][2]=0.f; acc[t][3]=0.f; }

#pragma unroll
    for (int ch = 0; ch < 4; ++ch) {
        const size_t ko = (size_t)(kz * 4 + ch) * 32;
        const bf16x8 a = *(const bf16x8*)(arow + ko);
#pragma unroll
        for (int t = 0; t < 4; ++t) {
            const bf16x8 bv = *(const bf16x8*)(brow + (size_t)t * 16 * 1024 + ko);
            acc[t] = __builtin_amdgcn_mfma_f32_16x16x32_bf16(a, bv, acc[t], 0, 0, 0);
        }
    }
    float* outp = r2p + (size_t)kz * (NG * 512);
#pragma unroll
    for (int t = 0; t < 4; ++t)
#pragma unroll
        for (int r = 0; r < 4; ++r)
            outp[(size_t)(mt * 16 + q * 4 + r) * 512 + n0 + t * 16 + nlo] = acc[t][r];
}

// K8: out = sum_kz r2p + fc2_b
__global__ __launch_bounds__(256) void k_red2(
    const float* __restrict__ r2p, const float* __restrict__ b2, float* __restrict__ out)
{
    const size_t i = ((size_t)blockIdx.x * 256 + threadIdx.x) * 4;
    const size_t S = (size_t)NG * 512;
    float4 s = *(const float4*)(r2p + i);
#pragma unroll
    for (int k = 1; k < 8; ++k) {
        const float4 t = *(const float4*)(r2p + k * S + i);
        s.x += t.x; s.y += t.y; s.z += t.z; s.w += t.w;
    }
    const float4 bb = *(const float4*)(b2 + (i & 511));
    s.x += bb.x; s.y += bb.y; s.z += bb.z; s.w += bb.w;
    *(float4*)(out + i) = s;
}

// ---------------------------------------------------------------------------
extern "C" void kernel_launch(void* const* d_in, const int* in_sizes, int n_in,
                              void* d_out, int out_size, void* d_ws, size_t ws_size,
                              hipStream_t stream)
{
    const float* x0   = (const float*)d_in[0];
    const float* x1   = (const float*)d_in[1];
    const float* x2   = (const float*)d_in[2];
    const int*   ei0  = (const int*)d_in[3];
    const int*   ei1  = (const int*)d_in[4];
    const int*   ei2  = (const int*)d_in[5];
    const float* ea0  = (const float*)d_in[6];
    const float* ea1  = (const float*)d_in[7];
    const float* ea2  = (const float*)d_in[8];
    const float* gc1w = (const float*)d_in[9];
    const float* gc1b = (const float*)d_in[10];
    const float* gc4w = (const float*)d_in[11];
    const float* gc4b = (const float*)d_in[12];
    const float* fc1w = (const float*)d_in[13];
    const float* fc1b = (const float*)d_in[14];
    const float* fc2w = (const float*)d_in[15];
    const float* fc2b = (const float*)d_in[16];

    float*    ws   = (float*)d_ws;
    float*    xw0  = ws + XW0_OFF;
    bf16_t*   xw1b = (bf16_t*)(ws + XW1B_OFF);
    bf16_t*   wb   = (bf16_t*)(ws + WB_OFF);
    bf16_t*   wb2  = (bf16_t*)(ws + WB2_OFF);
    bf16_t*   wxt  = (bf16_t*)(ws + WXT_OFF);
    unsigned* epk  = (unsigned*)(ws + EPK_OFF);
    int*      offsg= (int*)(ws + OFFS_OFF);
    bf16_t*   hb   = (bf16_t*)(ws + HB_OFF);
    bf16_t*   h1b  = (bf16_t*)(ws + H1B_OFF);
    float*    r1p  = ws + R1P_OFF;   // aliases epk/offs (dead after k_g2)
    float*    r2p  = ws + R2P_OFF;   // aliases wb (dead after k_fc1)
    bf16_t*   fbp  = (bf16_t*)(ws + FB_OFF);  // aliases xw0 (dead after k_g1)
    float*    out  = (float*)d_out;

    k_prep <<<NCASTB + NCASTB2 + 1, 256, 0, stream>>>(fc1w, fc2w, gc1w, wb, wb2, wxt);
    k_csr  <<<NG, 256, 0, stream>>>(ei0, ei1, ei2, ea0, ea1, ea2, epk, offsg);
    k_xw   <<<dim3(5, NG), 256, 0, stream>>>(x0, x1, x2, wxt, xw0, xw1b);
    k_g1   <<<dim3(4, NG), 256, 0, stream>>>(xw1b, xw0, epk, offsg, gc1b, hb);
    k_g2   <<<dim3(4, NG), 256, 0, stream>>>(hb, epk, offsg, gc4w, gc4b, fbp);
    k_fc1  <<<dim3(12, 4, 4), 256, 0, stream>>>(fbp, wb, r1p);
    k_red1 <<<NG, 256, 0, stream>>>(r1p, fc1b, h1b);
    k_fc2m <<<dim3(12, 2, 8), 256, 0, stream>>>(h1b, wb2, r2p);
    k_red2 <<<96, 256, 0, stream>>>(r2p, fc2b, out);
}